// Round 11
// baseline (51.164 us; speedup 1.0000x reference)
//
#include <hip/hip_runtime.h>
#include <math.h>

#define CIN  32
#define COUT 32
#define BB   4
#define HH   80
#define WW   80
#define HW   (HH * WW)
#define NOUT (BB * COUT * HW)   // 819200
#define TH   16                 // output rows per block stripe
#define XR   20                 // haloed rows
#define XC   88                 // haloed cols, padded
#define TILE (XR * XC)          // 1760
#define NT   320                // 8 co x (2 row-groups x 20 col-groups)

typedef float v4f __attribute__((ext_vector_type(4)));

__device__ __forceinline__ float max3f(float a, float b, float c) {
    float d;
    asm("v_max3_f32 %0, %1, %2, %3" : "=v"(d) : "v"(a), "v"(b), "v"(c));
    return d;
}

__device__ __forceinline__ void load_lds4(const float* g, float* l) {
    __builtin_amdgcn_global_load_lds(
        (const __attribute__((address_space(1))) void*)g,
        (__attribute__((address_space(3))) void*)l, 4, 0, 0);
}

// Thread tile: 8 rows x 4 cols x 1 co  -> x LDS reads amortized over 8 rows
// (24 b128 x + 10 b128 w per 32 outputs = 1.06 b128/output-ci, vs 2.2 before).
// Weights resident in 25 VGPRs per ci (per-thread co). Block: 16r x 80c x 8co,
// CP=CIN/NP ci, all CP x-tiles LDS-resident, ONE barrier. Partials to d_ws.
template<int NP>
__global__ __launch_bounds__(NT, 4) void semiconv_kernel(
    const float* __restrict__ x,     // [B, CIN, H, W]
    const float* __restrict__ w,     // [COUT, CIN, 5, 5]
    float* __restrict__ dst)         // partials [NP][NOUT]
{
    constexpr int CP = CIN / NP;
    __shared__ __align__(16) float xs[CP * TILE];
    __shared__ __align__(16) float wl[CP * 8 * 40];   // [k][co'][m][8] (n 0..4 + 3 pad)

    const int tid = threadIdx.x;
    const int bh  = blockIdx.x;               // 0..4 row stripe
    const int cg  = blockIdx.y;               // 0..3 co-group of 8
    const int zz  = blockIdx.z;               // b * NP + part
    const int b    = zz / NP;
    const int part = zz % NP;
    const int ci0  = part * CP;
    const int h0   = bh * TH;
    const int co0  = cg * 8;

    // thread -> (co', row-group, col-group)
    const int co_t = tid / 40;                // 0..7
    const int rem  = tid % 40;
    const int rg   = rem / 20;                // 0..1 (8-row groups)
    const int cgx  = rem % 20;                // 0..19 (4-col groups)

    // ---- staging offsets (6 slots of NT) ----
    int goff[6];
    #pragma unroll
    for (int i = 0; i < 6; ++i) {
        int idx = tid + i * NT;
        int r = idx / XC, c = idx % XC;
        int gr = h0 + r - 2, gc = c - 2;
        bool in = (idx < TILE) && gr >= 0 && gr < HH && gc >= 0 && gc < WW;
        goff[i] = in ? (gr * WW + gc) : -1;
    }
    const bool has6 = (tid < TILE - 5 * NT);   // tid < 160

    // ---- issue ALL tile DMAs up front (global -> LDS, lane-linear dest) ----
    const float* xb0 = x + (size_t)(b * CIN + ci0) * HW;
    const int wave64 = tid & ~63;
    #pragma unroll
    for (int t = 0; t < CP; ++t) {
        const float* xp = xb0 + (size_t)t * HW;
        float* xd = xs + t * TILE;
        #pragma unroll
        for (int i = 0; i < 5; ++i)
            if (goff[i] >= 0) load_lds4(xp + goff[i], xd + i * NT + wave64);
        if (has6 && goff[5] >= 0) load_lds4(xp + goff[5], xd + 5 * NT + wave64);
    }

    // ---- weight staging: [k][co'][m][8], n<5 real, pad zeros ----
    for (int idx = tid; idx < CP * 320; idx += NT) {
        int n = idx & 7, t = idx >> 3;
        int m = t % 5, u = t / 5;
        int cop = u & 7, k = u >> 3;
        wl[idx] = (n < 5)
            ? w[((size_t)(co0 + cop) * CIN + ci0 + k) * 25 + m * 5 + n] : 0.0f;
    }

    // ---- -inf prefill of OOB/pad cells (disjoint from DMA slots) ----
    #pragma unroll
    for (int i = 0; i < 6; ++i) {
        int idx = tid + i * NT;
        if (idx < TILE && goff[i] < 0) {
            #pragma unroll
            for (int t = 0; t < CP; ++t) xs[t * TILE + idx] = -INFINITY;
        }
    }

    float s[8][4];
    #pragma unroll
    for (int r = 0; r < 8; ++r)
        #pragma unroll
        for (int j = 0; j < 4; ++j) s[r][j] = 0.f;

    const int xoff = rg * 8 * XC + cgx * 4;   // thread's tile base
    const int woff = co_t * 40;               // thread's co within k-chunk

    __syncthreads();   // the ONLY barrier

    #pragma unroll 1
    for (int k = 0; k < CP; ++k) {
        const float* xk = xs + k * TILE + xoff;
        const float* wk = wl + k * 320 + woff;

        // 25 weights resident in VGPRs (10 aligned b128, <=2 addrs per wave)
        float wm[5][5];
        #pragma unroll
        for (int m = 0; m < 5; ++m) {
            v4f W0 = *(const v4f*)(wk + m * 8);
            v4f W1 = *(const v4f*)(wk + m * 8 + 4);
            wm[m][0] = W0.x; wm[m][1] = W0.y; wm[m][2] = W0.z;
            wm[m][3] = W0.w; wm[m][4] = W1.x;
        }

        float acc[8][4];
        #pragma unroll
        for (int rho = 0; rho < 12; ++rho) {   // stream 12 x-rows, each read ONCE
            v4f A = *(const v4f*)(xk + rho * XC);
            v4f C = *(const v4f*)(xk + rho * XC + 4);
            float xr[8] = {A.x, A.y, A.z, A.w, C.x, C.y, C.z, C.w};
            #pragma unroll
            for (int m = 0; m < 5; ++m) {
                const int r = rho - m;          // out-row fed by (rho, m)
                if (r < 0 || r > 7) continue;
                #pragma unroll
                for (int j = 0; j < 4; ++j) {
                    float t = max3f(xr[j] + wm[m][0], xr[j + 1] + wm[m][1],
                                    xr[j + 2] + wm[m][2]);
                    float u = fmaxf(xr[j + 3] + wm[m][3], xr[j + 4] + wm[m][4]);
                    acc[r][j] = (m == 0) ? fmaxf(t, u) : max3f(acc[r][j], t, u);
                }
            }
        }
        #pragma unroll
        for (int r = 0; r < 8; ++r)
            #pragma unroll
            for (int j = 0; j < 4; ++j) s[r][j] += acc[r][j];
    }

    // ---- epilogue: 8 b128 partial stores ----
    float* o = dst + (size_t)part * NOUT
             + (((size_t)b * COUT + co0 + co_t) * HH + (h0 + rg * 8)) * WW
             + cgx * 4;
    #pragma unroll
    for (int r = 0; r < 8; ++r) {
        v4f v = {s[r][0], s[r][1], s[r][2], s[r][3]};
        *(v4f*)(o + r * WW) = v;
    }
}

template<int NP>
__global__ __launch_bounds__(256) void reduceN_kernel(
    const float* __restrict__ ws, const float* __restrict__ bias,
    float* __restrict__ out)
{
    int i4 = blockIdx.x * 256 + threadIdx.x;        // 0..204799
    const float4* p = reinterpret_cast<const float4*>(ws);
    float4 r = p[i4];
    #pragma unroll
    for (int q = 1; q < NP; ++q) {
        float4 t = p[i4 + (size_t)q * (NOUT / 4)];
        r.x += t.x; r.y += t.y; r.z += t.z; r.w += t.w;
    }
    int co = (i4 / (HW / 4)) & (COUT - 1);
    float bc = bias[co];
    r.x += bc; r.y += bc; r.z += bc; r.w += bc;
    reinterpret_cast<float4*>(out)[i4] = r;
}

// Last-resort correct path (only if ws is unexpectedly tiny).
__global__ __launch_bounds__(256) void naive_kernel(
    const float* __restrict__ x, const float* __restrict__ w,
    const float* __restrict__ bias, float* __restrict__ out)
{
    int o = blockIdx.x * 256 + threadIdx.x;
    if (o >= NOUT) return;
    int wcol = o % WW, h = (o / WW) % HH, co = (o / HW) % COUT, b = o / (COUT * HW);
    float sum = 0.f;
    for (int ci = 0; ci < CIN; ++ci) {
        float mx = -INFINITY;
        for (int m = 0; m < 5; ++m) {
            int gr = h + m - 2;
            if (gr < 0 || gr >= HH) continue;
            for (int n = 0; n < 5; ++n) {
                int gc = wcol + n - 2;
                if (gc < 0 || gc >= WW) continue;
                float v = x[((size_t)(b * CIN + ci)) * HW + gr * WW + gc]
                        + w[((size_t)(co * CIN + ci)) * 25 + m * 5 + n];
                mx = fmaxf(mx, v);
            }
        }
        sum += mx;
    }
    out[o] = sum + bias[co];
}

extern "C" void kernel_launch(void* const* d_in, const int* in_sizes, int n_in,
                              void* d_out, int out_size, void* d_ws, size_t ws_size,
                              hipStream_t stream) {
    const float* x    = (const float*)d_in[0];
    const float* w    = (const float*)d_in[1];
    const float* bias = (const float*)d_in[2];
    float* out        = (float*)d_out;

    const size_t need8 = 8ull * NOUT * sizeof(float);  // 26.2 MB
    const size_t need4 = 4ull * NOUT * sizeof(float);  // 13.1 MB

    if (ws_size >= need8) {
        dim3 grid(HH / TH, COUT / 8, BB * 8);          // 5 x 4 x 32 = 640 blocks
        semiconv_kernel<8><<<grid, NT, 0, stream>>>(x, w, (float*)d_ws);
        reduceN_kernel<8><<<NOUT / 4 / 256, 256, 0, stream>>>((const float*)d_ws, bias, out);
    } else if (ws_size >= need4) {
        dim3 grid(HH / TH, COUT / 8, BB * 4);          // 320 blocks (CP=8: 66 KB LDS)
        semiconv_kernel<4><<<grid, NT, 0, stream>>>(x, w, (float*)d_ws);
        reduceN_kernel<4><<<NOUT / 4 / 256, 256, 0, stream>>>((const float*)d_ws, bias, out);
    } else {
        naive_kernel<<<(NOUT + 255) / 256, 256, 0, stream>>>(x, w, bias, out);
    }
}

// Round 12
// 43.895 us; speedup vs baseline: 1.1656x; 1.1656x over previous
//
#include <hip/hip_runtime.h>
#include <math.h>

#define CIN  32
#define COUT 32
#define BB   4
#define HH   80
#define WW   80
#define HW   (HH * WW)
#define NOUT (BB * COUT * HW)   // 819200
#define TH   16                 // output rows per block stripe
#define XR   20                 // haloed rows
#define XC   88                 // haloed cols (88 dw stride: measured ~conflict-free)
#define TILE (XR * XC)          // 1760
#define NT   512                // 8 waves; one co per WAVE

typedef float v4f __attribute__((ext_vector_type(4)));

__device__ __forceinline__ float max3f(float a, float b, float c) {
    float d;
    asm("v_max3_f32 %0, %1, %2, %3" : "=v"(d) : "v"(a), "v"(b), "v"(c));
    return d;
}

__device__ __forceinline__ void load_lds4(const float* g, float* l) {
    __builtin_amdgcn_global_load_lds(
        (const __attribute__((address_space(1))) void*)g,
        (__attribute__((address_space(3))) void*)l, 4, 0, 0);
}

// Block = 16r x 80c stripe, 8 waves, ONE co per wave (readfirstlane-uniform ->
// weights via s_load into SGPRs, v_add v,s,v: ZERO LDS traffic for w).
// Lane = 1 output row x 20 cols: per k, 5 rows x 6 ds_read_b128 feed a 1-D
// streaming j-loop (shape hipcc schedules well). CP x-tiles all LDS-resident,
// one barrier. Partials to d_ws, summed by reduceN (bias there).
template<int NP>
__global__ __launch_bounds__(NT, 4) void semiconv_kernel(
    const float* __restrict__ x,     // [B, CIN, H, W]
    const float* __restrict__ w,     // [COUT, CIN, 5, 5]
    float* __restrict__ dst)         // partials [NP][NOUT]
{
    constexpr int CP = CIN / NP;
    __shared__ __align__(16) float xs[CP][TILE];

    const int tid = threadIdx.x;
    const int bh  = blockIdx.x;               // 0..4 row stripe
    const int cog = blockIdx.y;               // 0..3 co-octet
    const int zz  = blockIdx.z;               // b * NP + part
    const int b    = zz / NP;
    const int part = zz % NP;
    const int ci0  = part * CP;
    const int h0   = bh * TH;

    const int wave = __builtin_amdgcn_readfirstlane(tid >> 6);  // provably SGPR
    const int lane = tid & 63;
    const int co   = cog * 8 + wave;          // wave-uniform
    const int r    = lane >> 2;               // 0..15 output row
    const int g    = lane & 3;                // col block: 20g..20g+19

    // ---- staging offsets: 4 slot-rounds of NT (last partial) ----
    int goff[4];
    #pragma unroll
    for (int i = 0; i < 4; ++i) {
        int idx = tid + i * NT;
        int rr = idx / XC, cc = idx % XC;
        int gr = h0 + rr - 2, gc = cc - 2;
        bool in = (idx < TILE) && gr >= 0 && gr < HH && gc >= 0 && gc < WW;
        goff[i] = in ? (gr * WW + gc) : -1;
    }

    // ---- issue ALL tile DMAs up front (lane-linear LDS dest) ----
    const float* xb0 = x + (size_t)(b * CIN + ci0) * HW;
    const int wbase = wave * 64;
    #pragma unroll
    for (int t = 0; t < CP; ++t) {
        const float* xp = xb0 + (size_t)t * HW;
        #pragma unroll
        for (int i = 0; i < 4; ++i)
            if (goff[i] >= 0) load_lds4(xp + goff[i], &xs[t][i * NT + wbase]);
    }

    // ---- -inf prefill of OOB cells (disjoint from DMA slots) ----
    #pragma unroll
    for (int i = 0; i < 4; ++i) {
        int idx = tid + i * NT;
        if (idx < TILE && goff[i] < 0) {
            #pragma unroll
            for (int t = 0; t < CP; ++t) xs[t][idx] = -INFINITY;
        }
    }

    const float* wp = w + (size_t)(co * CIN + ci0) * 25;   // wave-uniform -> s_load

    float s[20];
    #pragma unroll
    for (int j = 0; j < 20; ++j) s[j] = 0.f;

    __syncthreads();   // the ONLY barrier: drains DMAs + prefill

    #pragma unroll 1
    for (int k = 0; k < CP; ++k) {
        // 25 uniform weights -> SGPRs
        float wk[25];
        #pragma unroll
        for (int j = 0; j < 25; ++j) wk[j] = wp[k * 25 + j];

        const float* xk = &xs[k][r * XC + 20 * g];
        float acc[20];
        #pragma unroll
        for (int m = 0; m < 5; ++m) {
            const float* xrow = xk + m * XC;
            float F[24];
            #pragma unroll
            for (int t = 0; t < 6; ++t) {
                v4f v = *(const v4f*)(xrow + 4 * t);
                F[4*t] = v.x; F[4*t+1] = v.y; F[4*t+2] = v.z; F[4*t+3] = v.w;
            }
            #pragma unroll
            for (int j = 0; j < 20; ++j) {
                float t1 = max3f(F[j]     + wk[5*m],
                                 F[j + 1] + wk[5*m + 1],
                                 F[j + 2] + wk[5*m + 2]);
                float t2 = fmaxf(F[j + 3] + wk[5*m + 3],
                                 F[j + 4] + wk[5*m + 4]);
                acc[j] = (m == 0) ? fmaxf(t1, t2) : max3f(acc[j], t1, t2);
            }
        }
        #pragma unroll
        for (int j = 0; j < 20; ++j) s[j] += acc[j];
    }

    // ---- epilogue: 5 b128 partial stores (1 row x 20 cols) ----
    float* o = dst + (size_t)part * NOUT
             + (((size_t)b * COUT + co) * HH + (h0 + r)) * WW + 20 * g;
    #pragma unroll
    for (int t = 0; t < 5; ++t) {
        v4f v = {s[4*t], s[4*t+1], s[4*t+2], s[4*t+3]};
        *(v4f*)(o + 4 * t) = v;
    }
}

template<int NP>
__global__ __launch_bounds__(256) void reduceN_kernel(
    const float* __restrict__ ws, const float* __restrict__ bias,
    float* __restrict__ out)
{
    int i4 = blockIdx.x * 256 + threadIdx.x;        // 0..204799
    const float4* p = reinterpret_cast<const float4*>(ws);
    float4 r = p[i4];
    #pragma unroll
    for (int q = 1; q < NP; ++q) {
        float4 t = p[i4 + (size_t)q * (NOUT / 4)];
        r.x += t.x; r.y += t.y; r.z += t.z; r.w += t.w;
    }
    int co = (i4 / (HW / 4)) & (COUT - 1);
    float bc = bias[co];
    r.x += bc; r.y += bc; r.z += bc; r.w += bc;
    reinterpret_cast<float4*>(out)[i4] = r;
}

// Last-resort correct path (only if ws is unexpectedly tiny).
__global__ __launch_bounds__(256) void naive_kernel(
    const float* __restrict__ x, const float* __restrict__ w,
    const float* __restrict__ bias, float* __restrict__ out)
{
    int o = blockIdx.x * 256 + threadIdx.x;
    if (o >= NOUT) return;
    int wcol = o % WW, h = (o / WW) % HH, co = (o / HW) % COUT, b = o / (COUT * HW);
    float sum = 0.f;
    for (int ci = 0; ci < CIN; ++ci) {
        float mx = -INFINITY;
        for (int m = 0; m < 5; ++m) {
            int gr = h + m - 2;
            if (gr < 0 || gr >= HH) continue;
            for (int n = 0; n < 5; ++n) {
                int gc = wcol + n - 2;
                if (gc < 0 || gc >= WW) continue;
                float v = x[((size_t)(b * CIN + ci)) * HW + gr * WW + gc]
                        + w[((size_t)(co * CIN + ci)) * 25 + m * 5 + n];
                mx = fmaxf(mx, v);
            }
        }
        sum += mx;
    }
    out[o] = sum + bias[co];
}

extern "C" void kernel_launch(void* const* d_in, const int* in_sizes, int n_in,
                              void* d_out, int out_size, void* d_ws, size_t ws_size,
                              hipStream_t stream) {
    const float* x    = (const float*)d_in[0];
    const float* w    = (const float*)d_in[1];
    const float* bias = (const float*)d_in[2];
    float* out        = (float*)d_out;

    const size_t need8 = 8ull * NOUT * sizeof(float);  // 26.2 MB
    const size_t need4 = 4ull * NOUT * sizeof(float);  // 13.1 MB

    if (ws_size >= need8) {
        dim3 grid(HH / TH, COUT / 8, BB * 8);          // 5 x 4 x 32 = 640 blocks
        semiconv_kernel<8><<<grid, NT, 0, stream>>>(x, w, (float*)d_ws);
        reduceN_kernel<8><<<NOUT / 4 / 256, 256, 0, stream>>>((const float*)d_ws, bias, out);
    } else if (ws_size >= need4) {
        dim3 grid(HH / TH, COUT / 8, BB * 4);          // 320 blocks (CP=8: 56 KB LDS)
        semiconv_kernel<4><<<grid, NT, 0, stream>>>(x, w, (float*)d_ws);
        reduceN_kernel<4><<<NOUT / 4 / 256, 256, 0, stream>>>((const float*)d_ws, bias, out);
    } else {
        naive_kernel<<<(NOUT + 255) / 256, 256, 0, stream>>>(x, w, bias, out);
    }
}

// Round 13
// 40.701 us; speedup vs baseline: 1.2571x; 1.0785x over previous
//
#include <hip/hip_runtime.h>
#include <math.h>

#define CIN  32
#define COUT 32
#define BB   4
#define HH   80
#define WW   80
#define HW   (HH * WW)
#define NOUT (BB * COUT * HW)   // 819200
#define TH   16                 // output rows per block stripe
#define XR   20                 // haloed rows
#define XC   88                 // haloed cols, padded
#define TILE (XR * XC)          // 1760 = 5 waves x 352 cells
#define WSLICE 352              // cells per wave (5.5 x 64)
#define NT   320                // 16 rows x 20 col-groups (4 cols each)

typedef float v4f __attribute__((ext_vector_type(4)));

__device__ __forceinline__ float max3f(float a, float b, float c) {
    float d;
    asm("v_max3_f32 %0, %1, %2, %3" : "=v"(d) : "v"(a), "v"(b), "v"(c));
    return d;
}

__device__ __forceinline__ void load_lds4(const float* g, float* l) {
    __builtin_amdgcn_global_load_lds(
        (const __attribute__((address_space(1))) void*)g,
        (__attribute__((address_space(3))) void*)l, 4, 0, 0);
}

// R6 engine + software pipeline: 3-buffer LDS ring, prefetch depth 2, raw
// s_barrier + counted s_waitcnt vmcnt(6) (tile k+2 stays in flight across the
// barrier -- no per-step vmcnt(0) drain). Each wave issues EXACTLY 6 DMAs per
// tile (contiguous 352-cell slice = 5 full + 1 half slot; fully-OOB slots
// issue a dummy DMA into a trash slot) so counted vmcnt is exact per wave.
template<int NP>
__global__ __launch_bounds__(NT, 7) void semiconv_kernel(
    const float* __restrict__ x,     // [B, CIN, H, W]
    const float* __restrict__ w,     // [COUT, CIN, 5, 5]
    const float* __restrict__ bias,  // [COUT]
    float* __restrict__ dst)         // partials [NP][NOUT] (or out if NP==1)
{
    constexpr int CP = CIN / NP;
    __shared__ __align__(16) float xs[3][TILE];
    __shared__ __align__(16) float wl[CP * 60];   // [k][m][12]: (co0,co1) pairs
    __shared__ __align__(16) float trash[64];     // dummy DMA target

    const int tid = threadIdx.x;
    const int bh  = blockIdx.x;               // 0..4 row stripe
    const int cp  = blockIdx.y;               // 0..15 co-pair
    const int zz  = blockIdx.z;               // b * NP + part
    const int b    = zz / NP;
    const int part = zz % NP;
    const int ci0  = part * CP;
    const int h0   = bh * TH;
    const int co0  = cp * 2;

    const int lane = tid & 63;
    const int wave = tid >> 6;                // 0..4
    const int wslot = wave * WSLICE;

    // ---- weight staging: contiguous runs -> interleaved [k][m][12] ----
    for (int idx = tid; idx < CP * 50; idx += NT) {
        int run = idx / (CP * 25);
        int r   = idx % (CP * 25);
        int k = r / 25, t = r % 25, m = t / 5, n = t % 5;
        wl[k * 60 + m * 12 + n * 2 + run] =
            w[((size_t)(co0 + run) * CIN + ci0) * 25 + r];
    }
    __builtin_amdgcn_sched_barrier(0);   // weights fully drained before DMAs

    // ---- per-wave staging offsets (6 slots; slot5 = half) + -inf prefill ----
    int goff[6];
    #pragma unroll
    for (int j = 0; j < 6; ++j) {
        int idx = wslot + j * 64 + lane;
        bool valid = (j < 5) || (lane < 32);
        int r = idx / XC, c = idx % XC;
        int gr = h0 + r - 2, gc = c - 2;
        bool in = valid && gr >= 0 && gr < HH && gc >= 0 && gc < WW;
        goff[j] = in ? (gr * WW + gc) : -1;
        if (valid && !in) {
            xs[0][idx] = -INFINITY; xs[1][idx] = -INFINITY; xs[2][idx] = -INFINITY;
        }
    }

    const float* xbase = x + (size_t)(b * CIN + ci0) * HW;

    // exactly 6 vmem ops per wave per tile (dummy keeps the count uniform)
    auto issue_tile = [&](int t, int bf) {
        const float* xp = xbase + (size_t)t * HW;
        #pragma unroll
        for (int j = 0; j < 6; ++j) {
            bool pred = (goff[j] >= 0);
            if (__any(pred)) {
                if (pred) load_lds4(xp + goff[j], &xs[bf][wslot + j * 64]);
            } else {
                load_lds4(xp, &trash[0]);
            }
        }
    };

    issue_tile(0, 0);
    issue_tile(1, 1);

    const int ty = tid / 20, tx = tid % 20, wc = tx * 4;
    const int xro = ty * XC + wc;
    float sA[4] = {0.f, 0.f, 0.f, 0.f}, sB[4] = {0.f, 0.f, 0.f, 0.f};

    asm volatile("s_waitcnt vmcnt(6) lgkmcnt(0)" ::: "memory");  // tile0 + all ds_writes done
    __builtin_amdgcn_s_barrier();
    __builtin_amdgcn_sched_barrier(0);

    #pragma unroll
    for (int k = 0; k < CP; ++k) {
        if (k + 2 < CP) issue_tile(k + 2, (k + 2) % 3);

        const float* xk = &xs[k % 3][xro];
        const float* wk = wl + k * 60;
        float aA[4], aB[4];
        #pragma unroll
        for (int m = 0; m < 5; ++m) {
            v4f A  = *(const v4f*)(xk + m * XC);
            v4f C  = *(const v4f*)(xk + m * XC + 4);
            v4f W0 = *(const v4f*)(wk + m * 12);
            v4f W1 = *(const v4f*)(wk + m * 12 + 4);
            v4f W2 = *(const v4f*)(wk + m * 12 + 8);
            float xr[8] = {A.x, A.y, A.z, A.w, C.x, C.y, C.z, C.w};
            float wa[5] = {W0.x, W0.z, W1.x, W1.z, W2.x};
            float wb[5] = {W0.y, W0.w, W1.y, W1.w, W2.y};
            #pragma unroll
            for (int j = 0; j < 4; ++j) {
                float t = max3f(xr[j] + wa[0], xr[j+1] + wa[1], xr[j+2] + wa[2]);
                float u = fmaxf(xr[j+3] + wa[3], xr[j+4] + wa[4]);
                aA[j] = (m == 0) ? fmaxf(t, u) : max3f(aA[j], t, u);
                t = max3f(xr[j] + wb[0], xr[j+1] + wb[1], xr[j+2] + wb[2]);
                u = fmaxf(xr[j+3] + wb[3], xr[j+4] + wb[4]);
                aB[j] = (m == 0) ? fmaxf(t, u) : max3f(aB[j], t, u);
            }
        }
        #pragma unroll
        for (int j = 0; j < 4; ++j) { sA[j] += aA[j]; sB[j] += aB[j]; }

        if (k < CP - 2) {
            asm volatile("s_waitcnt vmcnt(6) lgkmcnt(0)" ::: "memory");  // tile k+1 landed
        } else if (k == CP - 2) {
            asm volatile("s_waitcnt vmcnt(0) lgkmcnt(0)" ::: "memory");  // last tile landed
        }
        if (k < CP - 1) {
            __builtin_amdgcn_s_barrier();
            __builtin_amdgcn_sched_barrier(0);
        }
    }

    // ---- epilogue ----
    size_t oiA = (((size_t)b * COUT + co0) * HH + (h0 + ty)) * WW + wc;
    size_t oiB = oiA + (size_t)HW;
    v4f rA = {sA[0], sA[1], sA[2], sA[3]};
    v4f rB = {sB[0], sB[1], sB[2], sB[3]};
    float* o = dst;
    if (NP == 1) {
        float bcA = bias[co0], bcB = bias[co0 + 1];
        rA.x += bcA; rA.y += bcA; rA.z += bcA; rA.w += bcA;
        rB.x += bcB; rB.y += bcB; rB.z += bcB; rB.w += bcB;
    } else {
        o += (size_t)part * NOUT;
    }
    *(v4f*)(o + oiA) = rA;
    *(v4f*)(o + oiB) = rB;
}

template<int NP>
__global__ __launch_bounds__(256) void reduceN_kernel(
    const float* __restrict__ ws, const float* __restrict__ bias,
    float* __restrict__ out)
{
    int i4 = blockIdx.x * 256 + threadIdx.x;        // 0..204799
    const float4* p = reinterpret_cast<const float4*>(ws);
    float4 r = p[i4];
    #pragma unroll
    for (int q = 1; q < NP; ++q) {
        float4 t = p[i4 + (size_t)q * (NOUT / 4)];
        r.x += t.x; r.y += t.y; r.z += t.z; r.w += t.w;
    }
    int co = (i4 / (HW / 4)) & (COUT - 1);
    float bc = bias[co];
    r.x += bc; r.y += bc; r.z += bc; r.w += bc;
    reinterpret_cast<float4*>(out)[i4] = r;
}

// Last-resort correct path (only if ws is unexpectedly tiny).
__global__ __launch_bounds__(256) void naive_kernel(
    const float* __restrict__ x, const float* __restrict__ w,
    const float* __restrict__ bias, float* __restrict__ out)
{
    int o = blockIdx.x * 256 + threadIdx.x;
    if (o >= NOUT) return;
    int wcol = o % WW, h = (o / WW) % HH, co = (o / HW) % COUT, b = o / (COUT * HW);
    float sum = 0.f;
    for (int ci = 0; ci < CIN; ++ci) {
        float mx = -INFINITY;
        for (int m = 0; m < 5; ++m) {
            int gr = h + m - 2;
            if (gr < 0 || gr >= HH) continue;
            for (int n = 0; n < 5; ++n) {
                int gc = wcol + n - 2;
                if (gc < 0 || gc >= WW) continue;
                float v = x[((size_t)(b * CIN + ci)) * HW + gr * WW + gc]
                        + w[((size_t)(co * CIN + ci)) * 25 + m * 5 + n];
                mx = fmaxf(mx, v);
            }
        }
        sum += mx;
    }
    out[o] = sum + bias[co];
}

extern "C" void kernel_launch(void* const* d_in, const int* in_sizes, int n_in,
                              void* d_out, int out_size, void* d_ws, size_t ws_size,
                              hipStream_t stream) {
    const float* x    = (const float*)d_in[0];
    const float* w    = (const float*)d_in[1];
    const float* bias = (const float*)d_in[2];
    float* out        = (float*)d_out;

    const size_t need4 = 4ull * NOUT * sizeof(float);  // 13.1 MB
    const size_t need2 = 2ull * NOUT * sizeof(float);  // 6.55 MB

    if (ws_size >= need4) {
        dim3 grid(HH / TH, COUT / 2, BB * 4);          // 5 x 16 x 16 = 1280 blocks
        semiconv_kernel<4><<<grid, NT, 0, stream>>>(x, w, bias, (float*)d_ws);
        reduceN_kernel<4><<<NOUT / 4 / 256, 256, 0, stream>>>((const float*)d_ws, bias, out);
    } else if (ws_size >= need2) {
        dim3 grid(HH / TH, COUT / 2, BB * 2);          // 640 blocks
        semiconv_kernel<2><<<grid, NT, 0, stream>>>(x, w, bias, (float*)d_ws);
        reduceN_kernel<2><<<NOUT / 4 / 256, 256, 0, stream>>>((const float*)d_ws, bias, out);
    } else {
        naive_kernel<<<(NOUT + 255) / 256, 256, 0, stream>>>(x, w, bias, out);
    }
}